// Round 6
// baseline (5109.307 us; speedup 1.0000x reference)
//
#include <hip/hip_runtime.h>
#include <hip/hip_bf16.h>

// STGNN block: GAT(+LN) -> gx GEMM (split-bf16 MFMA) -> GRU scan(+LN fused)
// B=64 N=3 T=4096 D=64 H=128
constexpr int Tt = 4096;

using bhalf8 = __attribute__((ext_vector_type(8))) short;
using f32x4v = __attribute__((ext_vector_type(4))) float;

__device__ __forceinline__ float toF(float v) { return v; }
__device__ __forceinline__ float toF(__hip_bfloat16 v) { return __bfloat162float(v); }
__device__ __forceinline__ void stG(float* p, float v) { *p = v; }
__device__ __forceinline__ void stG(__hip_bfloat16* p, float v) { *p = __float2bfloat16(v); }

// round-to-nearest-even fp32 -> bf16 bits
__device__ __forceinline__ unsigned int bf16rn(float f) {
    unsigned int u = __float_as_uint(f);
    return (u + 0x7fffu + ((u >> 16) & 1u)) >> 16;
}

// DPP-based adds (VALU pipe, no DS usage). ctrl/rmask must be constexpr.
template <int CTRL, int RMASK>
__device__ __forceinline__ float dppadd(float x) {
    int y = __builtin_amdgcn_update_dpp(0, __float_as_int(x), CTRL, RMASK, 0xf, true);
    return x + __int_as_float(y);
}
// full-wave sum; lane 63 holds the total afterwards
__device__ __forceinline__ float wavesum(float x) {
    x = dppadd<0xB1, 0xf>(x);  // quad_perm {1,0,3,2}  = xor1
    x = dppadd<0x4E, 0xf>(x);  // quad_perm {2,3,0,1}  = xor2
    x = dppadd<0x141, 0xf>(x); // row_half_mirror      = xor4 (on 4-uniform data)
    x = dppadd<0x140, 0xf>(x); // row_mirror           = xor8 (on 8-uniform data)
    x = dppadd<0x142, 0xa>(x); // row_bcast15 -> rows 1,3
    x = dppadd<0x143, 0xc>(x); // row_bcast31 -> rows 2,3
    return x;
}

// ---------------------------------------------------------------------------
// K1a: per (b, 8-t tile): h = xW+b, softmax over j (N=3), mix, ELU, LayerNorm
// writes normalized h_sp (fp32) to hsp_out (d_out reused as scratch)
// ---------------------------------------------------------------------------
__global__ __launch_bounds__(256, 2) void k_gat(
    const float* __restrict__ x, const float* __restrict__ gat_W,
    const float* __restrict__ gat_b, const float* __restrict__ a_src,
    const float* __restrict__ a_dst, const float* __restrict__ attn_bias,
    const float* __restrict__ sn_g, const float* __restrict__ sn_b,
    float* __restrict__ hsp_out)
{
    __shared__ __align__(16) float Wl[64][128];
    __shared__ __align__(16) float hl[24][132];
    __shared__ __align__(16) float hsp[24][132];
    __shared__ __align__(16) float asr[128], ads[128], sng[128], snb[128];
    __shared__ float bias9[9], ssrc[24], sdst[24], alph[24][4];

    const int tid = threadIdx.x;
    const int b  = blockIdx.x >> 9;
    const int t0 = (blockIdx.x & 511) << 3;

    {
        const float4* src = (const float4*)gat_W;
        float4* dst = (float4*)&Wl[0][0];
        #pragma unroll
        for (int j = 0; j < 8; ++j) dst[tid + j*256] = src[tid + j*256];
    }
    if (tid < 128) { asr[tid] = a_src[tid]; ads[tid] = a_dst[tid]; }
    else { const int u = tid - 128; sng[u] = sn_g[u]; snb[u] = sn_b[u]; }
    if (tid < 9) bias9[tid] = attn_bias[tid];
    __syncthreads();

    const int tx = tid & 31, rg = tid >> 5;
    const int c0 = tx * 4;

    {   // h = x @ W + b for 3 nodes x 8 timesteps
        const float4 bq = *(const float4*)&gat_b[c0];
        float acc[3][4];
        #pragma unroll
        for (int n = 0; n < 3; ++n) {
            acc[n][0] = bq.x; acc[n][1] = bq.y; acc[n][2] = bq.z; acc[n][3] = bq.w;
        }
        const float* xbase = x + ((size_t)(b*3)*Tt + t0 + rg) * 64;
        #pragma unroll 4
        for (int d0 = 0; d0 < 64; d0 += 4) {
            float4 wq[4];
            wq[0] = *(const float4*)&Wl[d0+0][c0];
            wq[1] = *(const float4*)&Wl[d0+1][c0];
            wq[2] = *(const float4*)&Wl[d0+2][c0];
            wq[3] = *(const float4*)&Wl[d0+3][c0];
            #pragma unroll
            for (int n = 0; n < 3; ++n) {
                const float4 xv = *(const float4*)(xbase + (size_t)n*Tt*64 + d0);
                const float xs[4] = {xv.x, xv.y, xv.z, xv.w};
                #pragma unroll
                for (int j = 0; j < 4; ++j) {
                    acc[n][0] = fmaf(xs[j], wq[j].x, acc[n][0]);
                    acc[n][1] = fmaf(xs[j], wq[j].y, acc[n][1]);
                    acc[n][2] = fmaf(xs[j], wq[j].z, acc[n][2]);
                    acc[n][3] = fmaf(xs[j], wq[j].w, acc[n][3]);
                }
            }
        }
        #pragma unroll
        for (int n = 0; n < 3; ++n)
            *(float4*)&hl[n*8+rg][c0] = make_float4(acc[n][0], acc[n][1], acc[n][2], acc[n][3]);
    }
    __syncthreads();

    if (tid < 24) {   // attention logits
        float s1 = 0.f, s2 = 0.f;
        #pragma unroll 8
        for (int c = 0; c < 128; c += 4) {
            const float4 hv = *(const float4*)&hl[tid][c];
            const float4 av = *(const float4*)&asr[c];
            const float4 dv = *(const float4*)&ads[c];
            s1 += hv.x*av.x + hv.y*av.y + hv.z*av.z + hv.w*av.w;
            s2 += hv.x*dv.x + hv.y*dv.y + hv.z*dv.z + hv.w*dv.w;
        }
        ssrc[tid] = s1; sdst[tid] = s2;
    }
    __syncthreads();
    if (tid < 24) {   // softmax over source nodes j
        const int i = tid >> 3, tt = tid & 7;
        float sc[3], mx = -3.4e38f;
        #pragma unroll
        for (int j = 0; j < 3; ++j) {
            float v = ssrc[tid] + sdst[j*8 + tt];
            v = v > 0.f ? v : 0.2f * v;
            v += bias9[i*3 + j];
            sc[j] = v; mx = fmaxf(mx, v);
        }
        const float e0 = __expf(sc[0]-mx), e1 = __expf(sc[1]-mx), e2 = __expf(sc[2]-mx);
        const float inv = 1.f / (e0 + e1 + e2);
        alph[tid][0] = e0*inv; alph[tid][1] = e1*inv; alph[tid][2] = e2*inv;
    }
    __syncthreads();

    {   // mix over j + ELU
        #pragma unroll
        for (int i = 0; i < 3; ++i) {
            const int r = i*8 + rg;
            const float A0 = alph[r][0], A1 = alph[r][1], A2 = alph[r][2];
            const float4 h0 = *(const float4*)&hl[0*8+rg][c0];
            const float4 h1 = *(const float4*)&hl[1*8+rg][c0];
            const float4 h2 = *(const float4*)&hl[2*8+rg][c0];
            float4 o;
            o.x = A0*h0.x + A1*h1.x + A2*h2.x;
            o.y = A0*h0.y + A1*h1.y + A2*h2.y;
            o.z = A0*h0.z + A1*h1.z + A2*h2.z;
            o.w = A0*h0.w + A1*h1.w + A2*h2.w;
            o.x = o.x > 0.f ? o.x : __expf(o.x) - 1.f;
            o.y = o.y > 0.f ? o.y : __expf(o.y) - 1.f;
            o.z = o.z > 0.f ? o.z : __expf(o.z) - 1.f;
            o.w = o.w > 0.f ? o.w : __expf(o.w) - 1.f;
            *(float4*)&hsp[r][c0] = o;
        }
    }
    __syncthreads();

    {   // LayerNorm per row -> global
        const int wv = tid >> 6, lane = tid & 63;
        #pragma unroll
        for (int q = 0; q < 6; ++q) {
            const int r = wv*6 + q;
            const float2 v = *(const float2*)&hsp[r][lane*2];
            float s = v.x + v.y;
            float sq = v.x*v.x + v.y*v.y;
            #pragma unroll
            for (int msk = 1; msk < 64; msk <<= 1) {
                s  += __shfl_xor(s, msk, 64);
                sq += __shfl_xor(sq, msk, 64);
            }
            const float mu = s * (1.f/128.f);
            const float rstd = rsqrtf(sq*(1.f/128.f) - mu*mu + 1e-5f);
            const int n = r >> 3, tt = r & 7;
            float* orow = hsp_out + ((size_t)(b*3+n)*Tt + t0 + tt) * 128;
            const float2 g2 = *(const float2*)&sng[lane*2];
            const float2 b2 = *(const float2*)&snb[lane*2];
            float2 ov;
            ov.x = (v.x - mu)*rstd*g2.x + b2.x;
            ov.y = (v.y - mu)*rstd*g2.y + b2.y;
            *(float2*)&orow[lane*2] = ov;
        }
    }
}

// ---------------------------------------------------------------------------
// K1b: gx[row,g] = hsp[row,:] . W_ih[g,:] + b_ih[g] via split-bf16 MFMA.
// Block = 128 rows x 384 cols (3 chunks of 128). 4 waves, each 64x64 per chunk.
// Error ~2^-17 (Ah*Bh + Ah*Bl + Al*Bh), effectively fp32.
// ---------------------------------------------------------------------------
template <typename GT>
__global__ __launch_bounds__(256, 1) void k_gx(
    const float* __restrict__ hsp, const float* __restrict__ W_ih,
    const float* __restrict__ b_ih, GT* __restrict__ gx)
{
    // XOR-swizzled bf16 tiles: addr(row, kslot) = row*256 + ((kslot ^ (row&7))<<4)
    __shared__ __align__(16) unsigned char sAhi[128*256];
    __shared__ __align__(16) unsigned char sAlo[128*256];
    __shared__ __align__(16) unsigned char sBhi[128*256];
    __shared__ __align__(16) unsigned char sBlo[128*256];
    __shared__ float bi[384];

    const int tid = threadIdx.x;
    const size_t r0 = (size_t)blockIdx.x * 128;

    {   // stage A: 128 rows x 128 k fp32 -> bf16 hi/lo, swizzled
        const float4* src = (const float4*)(hsp + r0 * 128);
        #pragma unroll
        for (int it = 0; it < 16; ++it) {
            const int idx = tid + it*256;
            const int row = idx >> 5, c4 = idx & 31;
            const float4 v = src[idx];
            const unsigned int h0 = bf16rn(v.x), h1 = bf16rn(v.y),
                               h2 = bf16rn(v.z), h3 = bf16rn(v.w);
            const unsigned int l0 = bf16rn(v.x - __uint_as_float(h0 << 16));
            const unsigned int l1 = bf16rn(v.y - __uint_as_float(h1 << 16));
            const unsigned int l2 = bf16rn(v.z - __uint_as_float(h2 << 16));
            const unsigned int l3 = bf16rn(v.w - __uint_as_float(h3 << 16));
            const int addr = row*256 + ((((c4 >> 1) ^ (row & 7)) << 4)) + (c4 & 1)*8;
            *(uint2*)(sAhi + addr) = make_uint2(h0 | (h1 << 16), h2 | (h3 << 16));
            *(uint2*)(sAlo + addr) = make_uint2(l0 | (l1 << 16), l2 | (l3 << 16));
        }
        if (tid < 128) { bi[tid] = b_ih[tid]; bi[128 + tid] = b_ih[128 + tid]; }
        else           { bi[128 + tid] = b_ih[128 + tid]; }   // 256..383
    }

    const int wv = tid >> 6, lane = tid & 63;
    const int wr0 = (wv >> 1) * 64, wc0 = (wv & 1) * 64;
    const int lq = lane >> 4, lr = lane & 15;

    for (int ch = 0; ch < 3; ++ch) {
        __syncthreads();   // protect sB rewrite (covers A/bi on first iter)
        {   // stage B chunk: W_ih rows [ch*128, ch*128+128)
            const float4* src = (const float4*)(W_ih + (size_t)ch * 128 * 128);
            #pragma unroll
            for (int it = 0; it < 16; ++it) {
                const int idx = tid + it*256;
                const int row = idx >> 5, c4 = idx & 31;
                const float4 v = src[idx];
                const unsigned int h0 = bf16rn(v.x), h1 = bf16rn(v.y),
                                   h2 = bf16rn(v.z), h3 = bf16rn(v.w);
                const unsigned int l0 = bf16rn(v.x - __uint_as_float(h0 << 16));
                const unsigned int l1 = bf16rn(v.y - __uint_as_float(h1 << 16));
                const unsigned int l2 = bf16rn(v.z - __uint_as_float(h2 << 16));
                const unsigned int l3 = bf16rn(v.w - __uint_as_float(h3 << 16));
                const int addr = row*256 + ((((c4 >> 1) ^ (row & 7)) << 4)) + (c4 & 1)*8;
                *(uint2*)(sBhi + addr) = make_uint2(h0 | (h1 << 16), h2 | (h3 << 16));
                *(uint2*)(sBlo + addr) = make_uint2(l0 | (l1 << 16), l2 | (l3 << 16));
            }
        }
        __syncthreads();

        float bv[4];
        #pragma unroll
        for (int j = 0; j < 4; ++j) bv[j] = bi[ch*128 + wc0 + j*16 + lr];

        f32x4v acc[4][4];
        #pragma unroll
        for (int i = 0; i < 4; ++i)
            #pragma unroll
            for (int j = 0; j < 4; ++j)
                acc[i][j] = f32x4v{bv[j], bv[j], bv[j], bv[j]};

        #pragma unroll
        for (int ks = 0; ks < 4; ++ks) {
            bhalf8 ah[4], al[4], bh[4], bl[4];
            #pragma unroll
            for (int i = 0; i < 4; ++i) {
                const int row = wr0 + i*16 + lr;
                const int addr = row*256 + (((ks*4 + lq) ^ (row & 7)) << 4);
                ah[i] = *(const bhalf8*)(sAhi + addr);
                al[i] = *(const bhalf8*)(sAlo + addr);
            }
            #pragma unroll
            for (int j = 0; j < 4; ++j) {
                const int row = wc0 + j*16 + lr;
                const int addr = row*256 + (((ks*4 + lq) ^ (row & 7)) << 4);
                bh[j] = *(const bhalf8*)(sBhi + addr);
                bl[j] = *(const bhalf8*)(sBlo + addr);
            }
            #pragma unroll
            for (int i = 0; i < 4; ++i) {
                #pragma unroll
                for (int j = 0; j < 4; ++j) {
                    acc[i][j] = __builtin_amdgcn_mfma_f32_16x16x32_bf16(ah[i], bh[j], acc[i][j], 0, 0, 0);
                    acc[i][j] = __builtin_amdgcn_mfma_f32_16x16x32_bf16(ah[i], bl[j], acc[i][j], 0, 0, 0);
                    acc[i][j] = __builtin_amdgcn_mfma_f32_16x16x32_bf16(al[i], bh[j], acc[i][j], 0, 0, 0);
                }
            }
        }

        // epilogue: C row = (lane>>4)*4 + reg, col = lane&15 (m89-verified)
        #pragma unroll
        for (int i = 0; i < 4; ++i) {
            #pragma unroll
            for (int rr = 0; rr < 4; ++rr) {
                const size_t grow = r0 + wr0 + i*16 + lq*4 + rr;
                GT* orow = gx + grow*384 + ch*128 + wc0;
                #pragma unroll
                for (int j = 0; j < 4; ++j)
                    stG(&orow[j*16 + lr], acc[i][j][rr]);
            }
        }
    }
}

// ---------------------------------------------------------------------------
// K2: GRU scan, one block per (b,n) sequence (192 blocks), 256 threads.
// tid = g*2 + kh: thread owns W_hh rows {g, 128+g, 256+g} over k-half kh
// (192 VGPRs). h double-buffered in LDS -> ONE barrier per step.
// Pair-combine + LayerNorm reduce entirely via DPP (VALU pipe).
// ---------------------------------------------------------------------------
template <typename GT>
__global__ __launch_bounds__(256, 1) void k_gru(
    const GT* __restrict__ gx, const float* __restrict__ W_hh,
    const float* __restrict__ b_hh, const float* __restrict__ tn_g,
    const float* __restrict__ tn_b, float* __restrict__ out)
{
    __shared__ __align__(16) float hb[2][128];
    __shared__ __align__(8) float part[2][4][2];
    __shared__ float tng[128], tnb[128];

    const int tid = threadIdx.x;
    const int g = tid >> 1, kh = tid & 1;
    const int k0 = kh * 64;
    const int m = blockIdx.x;
    const int wvid = tid >> 6, lane = tid & 63;

    float wr[64], wz[64], wn[64];
    {
        const float4* p0 = (const float4*)(W_hh + ((size_t)(      g) * 128 + k0));
        const float4* p1 = (const float4*)(W_hh + ((size_t)(128 + g) * 128 + k0));
        const float4* p2 = (const float4*)(W_hh + ((size_t)(256 + g) * 128 + k0));
        #pragma unroll
        for (int i = 0; i < 16; ++i) {
            const float4 a = p0[i], b = p1[i], c = p2[i];
            wr[4*i+0]=a.x; wr[4*i+1]=a.y; wr[4*i+2]=a.z; wr[4*i+3]=a.w;
            wz[4*i+0]=b.x; wz[4*i+1]=b.y; wz[4*i+2]=b.z; wz[4*i+3]=b.w;
            wn[4*i+0]=c.x; wn[4*i+1]=c.y; wn[4*i+2]=c.z; wn[4*i+3]=c.w;
        }
    }
    const float bhr = b_hh[g], bhz = b_hh[128 + g], bhn = b_hh[256 + g];
    if (tid < 128) { hb[0][tid] = 0.f; tng[tid] = tn_g[tid]; tnb[tid] = tn_b[tid]; }

    const GT* gp = gx + (size_t)m * Tt * 384;
    float xr0 = toF(gp[g]),        xz0 = toF(gp[128 + g]),        xn0 = toF(gp[256 + g]);
    float xr1 = toF(gp[384 + g]),  xz1 = toF(gp[384 + 128 + g]),  xn1 = toF(gp[384 + 256 + g]);
    const GT* q = gp + 2*384;     // prefetch cursor (t+2)
    __syncthreads();

    #pragma unroll 2
    for (int t = 0; t < Tt; ++t) {
        float xr2 = 0.f, xz2 = 0.f, xn2 = 0.f;
        if (t + 2 < Tt) {
            xr2 = toF(q[g]); xz2 = toF(q[128 + g]); xn2 = toF(q[256 + g]);
        }
        q += 384;

        const float* h = hb[t & 1];
        float ar = 0.f, az = 0.f, an = 0.f;
        #pragma unroll
        for (int i = 0; i < 64; i += 4) {
            const float4 hv = *(const float4*)&h[k0 + i];
            ar = fmaf(wr[i+0], hv.x, ar); ar = fmaf(wr[i+1], hv.y, ar);
            ar = fmaf(wr[i+2], hv.z, ar); ar = fmaf(wr[i+3], hv.w, ar);
            az = fmaf(wz[i+0], hv.x, az); az = fmaf(wz[i+1], hv.y, az);
            az = fmaf(wz[i+2], hv.z, az); az = fmaf(wz[i+3], hv.w, az);
            an = fmaf(wn[i+0], hv.x, an); an = fmaf(wn[i+1], hv.y, an);
            an = fmaf(wn[i+2], hv.z, an); an = fmaf(wn[i+3], hv.w, an);
        }
        // pair combine (kh=0 + kh=1 halves) via DPP xor1 — VALU, no DS
        ar = dppadd<0xB1, 0xf>(ar);
        az = dppadd<0xB1, 0xf>(az);
        an = dppadd<0xB1, 0xf>(an);

        const float hprev = h[g];
        const float r = 1.f / (1.f + __expf(-(xr0 + ar + bhr)));
        const float z = 1.f / (1.f + __expf(-(xz0 + az + bhz)));
        float pre = xn0 + r * (an + bhn);
        pre = fminf(fmaxf(pre, -15.f), 15.f);
        const float e2 = __expf(2.f * pre);
        const float nn = (e2 - 1.f) / (e2 + 1.f);
        const float hnew = (1.f - z) * nn + z * hprev;

        hb[(t + 1) & 1][g] = hnew;           // other buffer: no race with readers
        // LN partials: each wave covers 32 g's, each duplicated in 2 lanes
        float s  = wavesum(hnew);
        float sq = wavesum(hnew * hnew);
        if (lane == 63) { part[t & 1][wvid][0] = s; part[t & 1][wvid][1] = sq; }
        __syncthreads();
        // all writes to hb[(t+1)&1] and part[t&1] are pre-barrier; the only
        // post-barrier reads touch part[t&1]; next iter writes part[(t+1)&1].
        float S  = part[t & 1][0][0] + part[t & 1][1][0] + part[t & 1][2][0] + part[t & 1][3][0];
        float SQ = part[t & 1][0][1] + part[t & 1][1][1] + part[t & 1][2][1] + part[t & 1][3][1];
        S *= 0.5f; SQ *= 0.5f;               // every g counted twice
        const float mu = S * (1.f / 128.f);
        const float rstd = rsqrtf(SQ * (1.f / 128.f) - mu * mu + 1e-5f);
        if (kh == 0)
            out[((size_t)m * Tt + t) * 128 + g] = (hnew - mu) * rstd * tng[g] + tnb[g];

        xr0 = xr1; xz0 = xz1; xn0 = xn1;
        xr1 = xr2; xz1 = xz2; xn1 = xn2;
    }
}

// ---------------------------------------------------------------------------
extern "C" void kernel_launch(void* const* d_in, const int* in_sizes, int n_in,
                              void* d_out, int out_size, void* d_ws, size_t ws_size,
                              hipStream_t stream)
{
    const float* x      = (const float*)d_in[0];
    const float* gat_W  = (const float*)d_in[1];
    const float* gat_b  = (const float*)d_in[2];
    const float* a_src  = (const float*)d_in[3];
    const float* a_dst  = (const float*)d_in[4];
    const float* a_bias = (const float*)d_in[5];
    const float* sn_g   = (const float*)d_in[6];
    const float* sn_b   = (const float*)d_in[7];
    const float* W_ih   = (const float*)d_in[8];
    const float* W_hh   = (const float*)d_in[9];
    const float* b_ih   = (const float*)d_in[10];
    const float* b_hh   = (const float*)d_in[11];
    const float* tn_g   = (const float*)d_in[12];
    const float* tn_b   = (const float*)d_in[13];
    float* out = (float*)d_out;

    // d_out doubles as scratch for normalized h_sp (fully overwritten by k_gru)
    float* hsp = out;

    const size_t gx_f32_bytes = (size_t)192 * 4096 * 384 * sizeof(float);
    const bool fp32gx = ws_size >= gx_f32_bytes;

    k_gat<<<64 * 512, 256, 0, stream>>>(x, gat_W, gat_b, a_src, a_dst, a_bias,
                                        sn_g, sn_b, hsp);
    if (fp32gx) {
        float* gxw = (float*)d_ws;
        k_gx<float><<<786432 / 128, 256, 0, stream>>>(hsp, W_ih, b_ih, gxw);
        k_gru<float><<<192, 256, 0, stream>>>(gxw, W_hh, b_hh, tn_g, tn_b, out);
    } else {
        // bf16 fallback if workspace can't hold fp32 gx (1.21 GB needed)
        __hip_bfloat16* gxw = (__hip_bfloat16*)d_ws;
        k_gx<__hip_bfloat16><<<786432 / 128, 256, 0, stream>>>(hsp, W_ih, b_ih, gxw);
        k_gru<__hip_bfloat16><<<192, 256, 0, stream>>>(gxw, W_hh, b_hh, tn_g, tn_b, out);
    }
    (void)in_sizes; (void)n_in; (void)out_size;
}